// Round 1
// baseline (26355.164 us; speedup 1.0000x reference)
//
#include <hip/hip_runtime.h>
#include <stdint.h>

typedef _Float16 f16;
typedef _Float16 f16x8 __attribute__((ext_vector_type(8)));
typedef float f32x16 __attribute__((ext_vector_type(16)));
typedef uint32_t u32;
typedef u32 u32x4 __attribute__((ext_vector_type(4)));

#define T_ 512

// ---- workspace layout (bytes) ----
#define SZ_W0  (64u*40u*2048u)          // layer0 packed weights: 64 hb * 40 ksteps * (1KB hi + 1KB lo)
#define SZ_W1  (64u*64u*2048u)          // layer1
#define OFF_W  0u
#define OFF_X  (SZ_W0 + SZ_W1)
#define SZ_X   (8192u*2048u)            // x packed: 512 t * 2 mt * 8 kc * 2KB
#define OFF_H0 (OFF_X + SZ_X)
#define SZ_HP  (3u*2u*32u*2048u)        // 3 rot bufs * 2 mt * 32 kc * 2KB
#define OFF_H1 (OFF_H0 + SZ_HP)
#define OFF_BIAS (OFF_H1 + SZ_HP)       // f32[2][2048]
#define OFF_BAR  (OFF_BIAS + 16384u)
#define WS_NEED  (size_t)(OFF_BAR + 64u)

#define LDS_ACC  131072                 // f32[32][33]
#define LDS_H    (131072 + 4352)        // f32[32][9]
#define LDS_TOTAL (131072 + 4352 + 1280)

__device__ __forceinline__ float sigm(float x) { return 1.0f / (1.0f + __expf(-x)); }
__device__ __forceinline__ float tanh_f(float x) {
  float e = __expf(2.0f * x);
  return 1.0f - 2.0f / (e + 1.0f);
}
__device__ __forceinline__ u32 f16bits(f16 v) {
  return (u32)__builtin_bit_cast(unsigned short, v);
}

// ---------------- weight prepack ----------------
// frag layout (32x32x16 f16): B[k][n]: lane = n (0..31) + 32*khalf; reg j: k = khalf*8 + j
// col order within 32-col tile: col = gate*8 + h8  (hidden-local h8 in 0..7)
__global__ void k_packw(const float* __restrict__ Wih0, const float* __restrict__ Whh0,
                        const float* __restrict__ Wih1, const float* __restrict__ Whh1,
                        char* __restrict__ wp) {
  int tid = blockIdx.x * 256 + threadIdx.x;
  int unit = tid >> 6, lane = tid & 63;
  if (unit >= 2560 + 4096) return;
  int layer, hb, ks;
  if (unit < 2560) { layer = 0; hb = unit / 40; ks = unit % 40; }
  else { int u = unit - 2560; layer = 1; hb = u >> 6; ks = u & 63; }
  int col = lane & 31;
  int gate = col >> 3, h8 = col & 7;
  int row = gate * 512 + hb * 8 + h8;
  int khalf = lane >> 5;
  u32 hi[4], lo[4];
#pragma unroll
  for (int jp = 0; jp < 4; ++jp) {
    u32 hv = 0, lv = 0;
#pragma unroll
    for (int e = 0; e < 2; ++e) {
      int j = jp * 2 + e;
      int k = ks * 16 + khalf * 8 + j;
      float w;
      if (layer == 0) w = (k < 128) ? Wih0[row * 128 + k] : Whh0[row * 512 + (k - 128)];
      else            w = (k < 512) ? Wih1[row * 512 + k] : Whh1[row * 512 + (k - 512)];
      f16 h_ = (f16)w; f16 l_ = (f16)(w - (float)h_);
      hv |= f16bits(h_) << (16 * e);
      lv |= f16bits(l_) << (16 * e);
    }
    hi[jp] = hv; lo[jp] = lv;
  }
  char* dst = wp + (layer ? SZ_W0 + (u32)hb * 64u * 2048u : (u32)hb * 40u * 2048u)
                 + (u32)ks * 2048u + (u32)lane * 16u;
  u32x4 vh = {hi[0], hi[1], hi[2], hi[3]};
  u32x4 vl = {lo[0], lo[1], lo[2], lo[3]};
  *(u32x4*)dst = vh;
  *(u32x4*)(dst + 1024) = vl;
}

// ---------------- x prepack ----------------
// A[m][k]: lane = m-row (0..31) + 32*khalf; reg j: k = khalf*8 + j  (same k-map as B -> cancels)
__global__ void k_packx(const float* __restrict__ x, char* __restrict__ xp) {
  int tid = blockIdx.x * 256 + threadIdx.x;
  int unit = tid >> 6, lane = tid & 63;   // units: 512*2*8 = 8192
  if (unit >= 8192) return;
  int t = unit >> 4, mt = (unit >> 3) & 1, kc = unit & 7;
  int b = mt * 32 + (lane & 31);
  int kbase = kc * 16 + (lane >> 5) * 8;
  const float* src = x + ((size_t)b * T_ + t) * 128 + kbase;
  u32 hi[4], lo[4];
#pragma unroll
  for (int jp = 0; jp < 4; ++jp) {
    u32 hv = 0, lv = 0;
#pragma unroll
    for (int e = 0; e < 2; ++e) {
      float w = src[jp * 2 + e];
      f16 h_ = (f16)w; f16 l_ = (f16)(w - (float)h_);
      hv |= f16bits(h_) << (16 * e);
      lv |= f16bits(l_) << (16 * e);
    }
    hi[jp] = hv; lo[jp] = lv;
  }
  char* dst = xp + (size_t)unit * 2048 + (u32)lane * 16;
  u32x4 vh = {hi[0], hi[1], hi[2], hi[3]};
  u32x4 vl = {lo[0], lo[1], lo[2], lo[3]};
  *(u32x4*)dst = vh;
  *(u32x4*)(dst + 1024) = vl;
}

// ---------------- init: out row0, h-pack init bufs, biases, barrier ----------------
__global__ void k_init(const float* __restrict__ bih0, const float* __restrict__ bhh0,
                       const float* __restrict__ bih1, const float* __restrict__ bhh1,
                       const float* __restrict__ h0in,
                       float* __restrict__ out, char* __restrict__ ws) {
  int tid = blockIdx.x * 256 + threadIdx.x;
  if (tid < 32768) {                       // out[:,0,:] = h0[-1,0,:]
    int b = tid >> 9, h = tid & 511;
    out[(size_t)b * 513 * 512 + h] = h0in[512 + h];
  } else if (tid < 32768 + 8192) {         // h-pack init: layer0 -> buf2, layer1 -> buf0
    int q = tid - 32768; int unit = q >> 6, lane = q & 63;  // 128 units
    int layer = unit >> 6, mt = (unit >> 5) & 1, kc = unit & 31;
    int Hh = kc * 16 + (lane >> 5) * 8;
    u32 hi[4], lo[4];
#pragma unroll
    for (int jp = 0; jp < 4; ++jp) {
      u32 hv = 0, lv = 0;
#pragma unroll
      for (int e = 0; e < 2; ++e) {
        float w = h0in[layer * 512 + Hh + jp * 2 + e];
        f16 h_ = (f16)w; f16 l_ = (f16)(w - (float)h_);
        hv |= f16bits(h_) << (16 * e);
        lv |= f16bits(l_) << (16 * e);
      }
      hi[jp] = hv; lo[jp] = lv;
    }
    int buf = layer ? 0 : 2;
    char* dst = ws + (layer ? OFF_H1 : OFF_H0)
                   + ((u32)(buf * 2 + mt) * 32 + (u32)kc) * 2048u + (u32)lane * 16u;
    u32x4 vh = {hi[0], hi[1], hi[2], hi[3]};
    u32x4 vl = {lo[0], lo[1], lo[2], lo[3]};
    *(u32x4*)dst = vh;
    *(u32x4*)(dst + 1024) = vl;
  } else if (tid < 32768 + 8192 + 4096) {  // combined biases
    int j = tid - 40960; int layer = j >> 11, jj = j & 2047;
    const float* a = layer ? bih1 : bih0;
    const float* b2 = layer ? bhh1 : bhh0;
    ((float*)(ws + OFF_BIAS))[layer * 2048 + jj] = a[jj] + b2[jj];
  } else if (tid == 32768 + 8192 + 4096) { // barrier counter
    *(u32*)(ws + OFF_BAR) = 0u;
  }
}

// ---------------- persistent recurrent kernel ----------------
// 256 WGs x 64 threads. wg -> (layer, mt, hb8). One 32x32 output tile per WG.
// LDS 133KB forces 1 WG/CU -> all 256 co-resident -> custom grid barrier is safe.
__global__ __launch_bounds__(64, 1)
void k_main(char* ws, const float* c0in, float* __restrict__ out) {
  extern __shared__ char smem[];
  const int wg = blockIdx.x;
  const int layer = wg >> 7, mt = (wg >> 6) & 1, hb = wg & 63;
  const int lane = threadIdx.x;
  const int nk = layer ? 64 : 40;

  // weights -> LDS (persistent; immune to per-step cache invalidation)
  {
    const char* wsrc = ws + OFF_W + (layer ? SZ_W0 + (u32)hb * 64u * 2048u : (u32)hb * 40u * 2048u);
    int nbytes = nk * 2048;
    for (int off = lane * 16; off < nbytes; off += 1024)
      *(u32x4*)(smem + off) = *(const u32x4*)(wsrc + off);
  }
  float* accS = (float*)(smem + LDS_ACC);   // [32][33]
  float* hS   = (float*)(smem + LDS_H);     // [32][9]
  const float* bias = (const float*)(ws + OFF_BIAS) + layer * 2048;
  const int hl = lane & 7, rg = lane >> 3;
  const int Hid = hb * 8 + hl;
  const float bi = bias[0 * 512 + Hid], bf = bias[1 * 512 + Hid];
  const float bg = bias[2 * 512 + Hid], bo = bias[3 * 512 + Hid];
  float c[4];
  { float ci = c0in[layer * 512 + Hid]; c[0] = c[1] = c[2] = c[3] = ci; }
  u32* bar = (u32*)(ws + OFF_BAR);
  const char* xp  = ws + OFF_X;
  const char* h0p = ws + OFF_H0;
  const char* h1p = ws + OFF_H1;
  char* h0pw = ws + OFF_H0;
  char* h1pw = ws + OFF_H1;
  const u32 lo16 = (u32)lane * 16u;
  __syncthreads();

  for (int s = 0; s <= T_; ++s) {
    const bool active = layer ? (s >= 1) : (s < T_);
    if (active) {
      const int t = layer ? (s - 1) : s;
      const int rbuf = (s + 2) % 3, wbuf = s % 3;
      const char* a0; const char* a1; int split;
      if (layer == 0) {
        a0 = xp + (u32)(t * 2 + mt) * 8u * 2048u;
        a1 = h0p + ((u32)(rbuf * 2 + mt) * 32u) * 2048u;
        split = 8;
      } else {
        a0 = h0p + ((u32)(rbuf * 2 + mt) * 32u) * 2048u;
        a1 = h1p + ((u32)(rbuf * 2 + mt) * 32u) * 2048u;
        split = 32;
      }
      f32x16 accA = {}, accB = {}, accC = {};   // 3 independent chains (acc forwarding)
#pragma unroll 8
      for (int ks = 0; ks < nk; ++ks) {
        const char* ab = (ks < split) ? (a0 + (u32)ks * 2048u) : (a1 + (u32)(ks - split) * 2048u);
        f16x8 ahi = *(const f16x8*)(ab + lo16);
        f16x8 alo = *(const f16x8*)(ab + 1024 + lo16);
        f16x8 bhi = *(const f16x8*)(smem + (u32)ks * 2048u + lo16);
        f16x8 blo = *(const f16x8*)(smem + (u32)ks * 2048u + 1024 + lo16);
        accA = __builtin_amdgcn_mfma_f32_32x32x16_f16(ahi, bhi, accA, 0, 0, 0);
        accB = __builtin_amdgcn_mfma_f32_32x32x16_f16(ahi, blo, accB, 0, 0, 0);
        accC = __builtin_amdgcn_mfma_f32_32x32x16_f16(alo, bhi, accC, 0, 0, 0);
      }
      // C layout (verified m74/m101): col = lane&31, row = (reg&3) + 8*(reg>>2) + 4*(lane>>5)
#pragma unroll
      for (int r = 0; r < 16; ++r) {
        int row = (r & 3) + 8 * (r >> 2) + 4 * (lane >> 5);
        accS[row * 33 + (lane & 31)] = accA[r] + accB[r] + accC[r];
      }
      __syncthreads();
      float* outp = out + (size_t)(mt * 32) * 513 * 512 + (size_t)(t + 1) * 512 + Hid;
#pragma unroll
      for (int j = 0; j < 4; ++j) {
        int row = rg * 4 + j;
        float gi = accS[row * 33 + hl] + bi;
        float gf = accS[row * 33 + 8 + hl] + bf;
        float gg = accS[row * 33 + 16 + hl] + bg;
        float go = accS[row * 33 + 24 + hl] + bo;
        float iv = sigm(gi), fv = sigm(gf), gv = tanh_f(gg), ov = sigm(go);
        float cc = fv * c[j] + iv * gv; c[j] = cc;
        float hv = ov * tanh_f(cc);
        hS[row * 9 + hl] = hv;
        if (layer) outp[(size_t)row * 513 * 512] = hv;
      }
      __syncthreads();
      // pack h into next-step A-frag layout; this WG owns k16-half (hb&1) of kchunk hb>>1
      if ((lane >> 5) == (hb & 1)) {
        int r32 = lane & 31;
        u32 hi[4], lo[4];
#pragma unroll
        for (int jp = 0; jp < 4; ++jp) {
          float v0 = hS[r32 * 9 + jp * 2], v1 = hS[r32 * 9 + jp * 2 + 1];
          f16 a_ = (f16)v0; f16 b_ = (f16)(v0 - (float)a_);
          f16 c_ = (f16)v1; f16 d_ = (f16)(v1 - (float)c_);
          hi[jp] = f16bits(a_) | (f16bits(c_) << 16);
          lo[jp] = f16bits(b_) | (f16bits(d_) << 16);
        }
        char* dst = (layer ? h1pw : h0pw)
                  + ((u32)(wbuf * 2 + mt) * 32 + (u32)(hb >> 1)) * 2048u + lo16;
        u32x4 vh = {hi[0], hi[1], hi[2], hi[3]};
        u32x4 vl = {lo[0], lo[1], lo[2], lo[3]};
        *(u32x4*)dst = vh;
        *(u32x4*)(dst + 1024) = vl;
      }
    }
    if (s < T_) {
      __threadfence();                                   // agent release: wbl2 -> LLC
      if (lane == 0) atomicAdd(bar, 1u);                 // device-scope RMW
      u32 target = 256u * (u32)(s + 1);
      while (__hip_atomic_load(bar, __ATOMIC_ACQUIRE, __HIP_MEMORY_SCOPE_AGENT) < target) {
        __builtin_amdgcn_s_sleep(1);
      }
    }
  }
}

extern "C" void kernel_launch(void* const* d_in, const int* in_sizes, int n_in,
                              void* d_out, int out_size, void* d_ws, size_t ws_size,
                              hipStream_t stream) {
  const float* x    = (const float*)d_in[0];
  const float* Wih0 = (const float*)d_in[1];
  const float* Whh0 = (const float*)d_in[2];
  const float* bih0 = (const float*)d_in[3];
  const float* bhh0 = (const float*)d_in[4];
  const float* Wih1 = (const float*)d_in[5];
  const float* Whh1 = (const float*)d_in[6];
  const float* bih1 = (const float*)d_in[7];
  const float* bhh1 = (const float*)d_in[8];
  const float* h0   = (const float*)d_in[9];
  const float* c0   = (const float*)d_in[10];
  float* out = (float*)d_out;
  char* ws = (char*)d_ws;
  if (ws_size < WS_NEED) return;  // diagnostic: absmax would stay exactly 0.1299

  hipFuncSetAttribute((const void*)k_main,
                      hipFuncAttributeMaxDynamicSharedMemorySize, LDS_TOTAL);

  k_packw<<<1664, 256, 0, stream>>>(Wih0, Whh0, Wih1, Whh1, ws + OFF_W);
  k_packx<<<2048, 256, 0, stream>>>(x, ws + OFF_X);
  k_init<<<177, 256, 0, stream>>>(bih0, bhh0, bih1, bhh1, h0, out, ws);
  k_main<<<256, 64, LDS_TOTAL, stream>>>(ws, c0, out);
}

// Round 2
// 12138.123 us; speedup vs baseline: 2.1713x; 2.1713x over previous
//
#include <hip/hip_runtime.h>
#include <stdint.h>

typedef _Float16 f16;
typedef _Float16 f16x8 __attribute__((ext_vector_type(8)));
typedef float f32x16 __attribute__((ext_vector_type(16)));
typedef uint32_t u32;
typedef u32 u32x4 __attribute__((ext_vector_type(4)));

#define T_ 512

// ---- workspace layout (bytes) ----
#define SZ_W0  (64u*40u*2048u)          // layer0 packed weights: 64 hb * 40 ksteps * (1KB hi + 1KB lo)
#define SZ_W1  (64u*64u*2048u)          // layer1
#define OFF_W  0u
#define OFF_X  (SZ_W0 + SZ_W1)
#define SZ_X   (8192u*2048u)            // x packed: 512 t * 2 mt * 8 kc * 2KB
#define OFF_H0 (OFF_X + SZ_X)
#define SZ_HP  (3u*2u*32u*2048u)        // 3 rot bufs * 2 mt * 32 kc * 2KB
#define OFF_H1 (OFF_H0 + SZ_HP)
#define OFF_BIAS (OFF_H1 + SZ_HP)       // f32[2][2048]
#define OFF_BAR  (OFF_BIAS + 16384u)    // 2 counters, 4KB apart (per-mt barriers)
#define WS_NEED  (size_t)(OFF_BAR + 8192u)

#define LDS_ACC  131072                 // f32[32][33]
#define LDS_H    (131072 + 4352)        // f32[32][9]
#define LDS_TOTAL (131072 + 4352 + 1280)

__device__ __forceinline__ float sigm(float x) { return 1.0f / (1.0f + __expf(-x)); }
__device__ __forceinline__ float tanh_f(float x) {
  float e = __expf(2.0f * x);
  return 1.0f - 2.0f / (e + 1.0f);
}
__device__ __forceinline__ u32 f16bits(f16 v) {
  return (u32)__builtin_bit_cast(unsigned short, v);
}
// write-through store to LLC (bypass L1/L2) -> release needs only vmcnt(0), no buffer_wbl2
__device__ __forceinline__ void store16_llc(void* p, u32x4 v) {
  asm volatile("global_store_dwordx4 %0, %1, off sc0 sc1" :: "v"(p), "v"(v) : "memory");
}

// ---------------- weight prepack ----------------
// frag layout (32x32x16 f16): B[k][n]: lane = n (0..31) + 32*khalf; reg j: k = khalf*8 + j
// col order within 32-col tile: col = gate*8 + h8  (hidden-local h8 in 0..7)
__global__ void k_packw(const float* __restrict__ Wih0, const float* __restrict__ Whh0,
                        const float* __restrict__ Wih1, const float* __restrict__ Whh1,
                        char* __restrict__ wp) {
  int tid = blockIdx.x * 256 + threadIdx.x;
  int unit = tid >> 6, lane = tid & 63;
  if (unit >= 2560 + 4096) return;
  int layer, hb, ks;
  if (unit < 2560) { layer = 0; hb = unit / 40; ks = unit % 40; }
  else { int u = unit - 2560; layer = 1; hb = u >> 6; ks = u & 63; }
  int col = lane & 31;
  int gate = col >> 3, h8 = col & 7;
  int row = gate * 512 + hb * 8 + h8;
  int khalf = lane >> 5;
  u32 hi[4], lo[4];
#pragma unroll
  for (int jp = 0; jp < 4; ++jp) {
    u32 hv = 0, lv = 0;
#pragma unroll
    for (int e = 0; e < 2; ++e) {
      int j = jp * 2 + e;
      int k = ks * 16 + khalf * 8 + j;
      float w;
      if (layer == 0) w = (k < 128) ? Wih0[row * 128 + k] : Whh0[row * 512 + (k - 128)];
      else            w = (k < 512) ? Wih1[row * 512 + k] : Whh1[row * 512 + (k - 512)];
      f16 h_ = (f16)w; f16 l_ = (f16)(w - (float)h_);
      hv |= f16bits(h_) << (16 * e);
      lv |= f16bits(l_) << (16 * e);
    }
    hi[jp] = hv; lo[jp] = lv;
  }
  char* dst = wp + (layer ? SZ_W0 + (u32)hb * 64u * 2048u : (u32)hb * 40u * 2048u)
                 + (u32)ks * 2048u + (u32)lane * 16u;
  u32x4 vh = {hi[0], hi[1], hi[2], hi[3]};
  u32x4 vl = {lo[0], lo[1], lo[2], lo[3]};
  *(u32x4*)dst = vh;
  *(u32x4*)(dst + 1024) = vl;
}

// ---------------- x prepack ----------------
// A[m][k]: lane = m-row (0..31) + 32*khalf; reg j: k = khalf*8 + j  (same k-map as B -> cancels)
__global__ void k_packx(const float* __restrict__ x, char* __restrict__ xp) {
  int tid = blockIdx.x * 256 + threadIdx.x;
  int unit = tid >> 6, lane = tid & 63;   // units: 512*2*8 = 8192
  if (unit >= 8192) return;
  int t = unit >> 4, mt = (unit >> 3) & 1, kc = unit & 7;
  int b = mt * 32 + (lane & 31);
  int kbase = kc * 16 + (lane >> 5) * 8;
  const float* src = x + ((size_t)b * T_ + t) * 128 + kbase;
  u32 hi[4], lo[4];
#pragma unroll
  for (int jp = 0; jp < 4; ++jp) {
    u32 hv = 0, lv = 0;
#pragma unroll
    for (int e = 0; e < 2; ++e) {
      float w = src[jp * 2 + e];
      f16 h_ = (f16)w; f16 l_ = (f16)(w - (float)h_);
      hv |= f16bits(h_) << (16 * e);
      lv |= f16bits(l_) << (16 * e);
    }
    hi[jp] = hv; lo[jp] = lv;
  }
  char* dst = xp + (size_t)unit * 2048 + (u32)lane * 16;
  u32x4 vh = {hi[0], hi[1], hi[2], hi[3]};
  u32x4 vl = {lo[0], lo[1], lo[2], lo[3]};
  *(u32x4*)dst = vh;
  *(u32x4*)(dst + 1024) = vl;
}

// ---------------- init: out row0, h-pack init bufs, biases, barriers ----------------
__global__ void k_init(const float* __restrict__ bih0, const float* __restrict__ bhh0,
                       const float* __restrict__ bih1, const float* __restrict__ bhh1,
                       const float* __restrict__ h0in,
                       float* __restrict__ out, char* __restrict__ ws) {
  int tid = blockIdx.x * 256 + threadIdx.x;
  if (tid < 32768) {                       // out[:,0,:] = h0[-1,0,:]
    int b = tid >> 9, h = tid & 511;
    out[(size_t)b * 513 * 512 + h] = h0in[512 + h];
  } else if (tid < 32768 + 8192) {         // h-pack init: layer0 -> buf2, layer1 -> buf0
    int q = tid - 32768; int unit = q >> 6, lane = q & 63;  // 128 units
    int layer = unit >> 6, mt = (unit >> 5) & 1, kc = unit & 31;
    int Hh = kc * 16 + (lane >> 5) * 8;
    u32 hi[4], lo[4];
#pragma unroll
    for (int jp = 0; jp < 4; ++jp) {
      u32 hv = 0, lv = 0;
#pragma unroll
      for (int e = 0; e < 2; ++e) {
        float w = h0in[layer * 512 + Hh + jp * 2 + e];
        f16 h_ = (f16)w; f16 l_ = (f16)(w - (float)h_);
        hv |= f16bits(h_) << (16 * e);
        lv |= f16bits(l_) << (16 * e);
      }
      hi[jp] = hv; lo[jp] = lv;
    }
    int buf = layer ? 0 : 2;
    char* dst = ws + (layer ? OFF_H1 : OFF_H0)
                   + ((u32)(buf * 2 + mt) * 32 + (u32)kc) * 2048u + (u32)lane * 16u;
    u32x4 vh = {hi[0], hi[1], hi[2], hi[3]};
    u32x4 vl = {lo[0], lo[1], lo[2], lo[3]};
    *(u32x4*)dst = vh;
    *(u32x4*)(dst + 1024) = vl;
  } else if (tid < 32768 + 8192 + 4096) {  // combined biases
    int j = tid - 40960; int layer = j >> 11, jj = j & 2047;
    const float* a = layer ? bih1 : bih0;
    const float* b2 = layer ? bhh1 : bhh0;
    ((float*)(ws + OFF_BIAS))[layer * 2048 + jj] = a[jj] + b2[jj];
  } else if (tid >= 45056 && tid < 45058) { // two per-mt barrier counters
    *(u32*)(ws + OFF_BAR + (u32)(tid - 45056) * 4096u) = 0u;
  }
}

// ---------------- persistent recurrent kernel ----------------
// 256 WGs x 64 threads. wg -> (mt, layer, hb8): mt=wg&1 so the two independent
// barrier groups interleave across XCDs. One 32x32 output tile per WG.
// LDS 133KB forces 1 WG/CU -> all 256 co-resident -> custom grid barrier is safe.
__global__ __launch_bounds__(64, 1)
void k_main(char* ws, const float* c0in, float* __restrict__ out) {
  extern __shared__ char smem[];
  const int wg = blockIdx.x;
  const int mt = wg & 1, layer = (wg >> 1) & 1, hb = wg >> 2;
  const int lane = threadIdx.x;
  const int nk = layer ? 64 : 40;

  // weights -> LDS (persistent; immune to per-step cache invalidation)
  {
    const char* wsrc = ws + OFF_W + (layer ? SZ_W0 + (u32)hb * 64u * 2048u : (u32)hb * 40u * 2048u);
    int nbytes = nk * 2048;
    for (int off = lane * 16; off < nbytes; off += 1024)
      *(u32x4*)(smem + off) = *(const u32x4*)(wsrc + off);
  }
  float* accS = (float*)(smem + LDS_ACC);   // [32][33]
  float* hS   = (float*)(smem + LDS_H);     // [32][9]
  const float* bias = (const float*)(ws + OFF_BIAS) + layer * 2048;
  const int hl = lane & 7, rg = lane >> 3;
  const int Hid = hb * 8 + hl;
  const float bi = bias[0 * 512 + Hid], bf = bias[1 * 512 + Hid];
  const float bg = bias[2 * 512 + Hid], bo = bias[3 * 512 + Hid];
  float c[4];
  { float ci = c0in[layer * 512 + Hid]; c[0] = c[1] = c[2] = c[3] = ci; }
  u32* bar = (u32*)(ws + OFF_BAR + (u32)mt * 4096u);   // per-mt barrier, 128 members
  const char* xp  = ws + OFF_X;
  const char* h0p = ws + OFF_H0;
  const char* h1p = ws + OFF_H1;
  char* h0pw = ws + OFF_H0;
  char* h1pw = ws + OFF_H1;
  const u32 lo16 = (u32)lane * 16u;
  __syncthreads();

  for (int s = 0; s <= T_; ++s) {
    const bool active = layer ? (s >= 1) : (s < T_);
    if (active) {
      const int t = layer ? (s - 1) : s;
      const int rbuf = (s + 2) % 3, wbuf = s % 3;
      const char* a0; const char* a1; int split;
      if (layer == 0) {
        a0 = xp + (u32)(t * 2 + mt) * 8u * 2048u;
        a1 = h0p + ((u32)(rbuf * 2 + mt) * 32u) * 2048u;
        split = 8;
      } else {
        a0 = h0p + ((u32)(rbuf * 2 + mt) * 32u) * 2048u;
        a1 = h1p + ((u32)(rbuf * 2 + mt) * 32u) * 2048u;
        split = 32;
      }
      f32x16 accA = {}, accB = {}, accC = {};   // 3 independent chains (acc forwarding)
#pragma unroll 8
      for (int ks = 0; ks < nk; ++ks) {
        const char* ab = (ks < split) ? (a0 + (u32)ks * 2048u) : (a1 + (u32)(ks - split) * 2048u);
        f16x8 ahi = *(const f16x8*)(ab + lo16);
        f16x8 alo = *(const f16x8*)(ab + 1024 + lo16);
        f16x8 bhi = *(const f16x8*)(smem + (u32)ks * 2048u + lo16);
        f16x8 blo = *(const f16x8*)(smem + (u32)ks * 2048u + 1024 + lo16);
        accA = __builtin_amdgcn_mfma_f32_32x32x16_f16(ahi, bhi, accA, 0, 0, 0);
        accB = __builtin_amdgcn_mfma_f32_32x32x16_f16(ahi, blo, accB, 0, 0, 0);
        accC = __builtin_amdgcn_mfma_f32_32x32x16_f16(alo, bhi, accC, 0, 0, 0);
      }
      // C layout (verified m74/m101): col = lane&31, row = (reg&3) + 8*(reg>>2) + 4*(lane>>5)
#pragma unroll
      for (int r = 0; r < 16; ++r) {
        int row = (r & 3) + 8 * (r >> 2) + 4 * (lane >> 5);
        accS[row * 33 + (lane & 31)] = accA[r] + accB[r] + accC[r];
      }
      __syncthreads();
      float* outp = out + (size_t)(mt * 32) * 513 * 512 + (size_t)(t + 1) * 512 + Hid;
#pragma unroll
      for (int j = 0; j < 4; ++j) {
        int row = rg * 4 + j;
        float gi = accS[row * 33 + hl] + bi;
        float gf = accS[row * 33 + 8 + hl] + bf;
        float gg = accS[row * 33 + 16 + hl] + bg;
        float go = accS[row * 33 + 24 + hl] + bo;
        float iv = sigm(gi), fv = sigm(gf), gv = tanh_f(gg), ov = sigm(go);
        float cc = fv * c[j] + iv * gv; c[j] = cc;
        float hv = ov * tanh_f(cc);
        hS[row * 9 + hl] = hv;
        if (layer) outp[(size_t)row * 513 * 512] = hv;
      }
      __syncthreads();
      // pack h into next-step A-frag layout; this WG owns k16-half (hb&1) of kchunk hb>>1.
      // Stores are write-through to LLC (sc0 sc1) -> no buffer_wbl2 needed at release.
      if ((lane >> 5) == (hb & 1)) {
        int r32 = lane & 31;
        u32 hi[4], lo[4];
#pragma unroll
        for (int jp = 0; jp < 4; ++jp) {
          float v0 = hS[r32 * 9 + jp * 2], v1 = hS[r32 * 9 + jp * 2 + 1];
          f16 a_ = (f16)v0; f16 b_ = (f16)(v0 - (float)a_);
          f16 c_ = (f16)v1; f16 d_ = (f16)(v1 - (float)c_);
          hi[jp] = f16bits(a_) | (f16bits(c_) << 16);
          lo[jp] = f16bits(b_) | (f16bits(d_) << 16);
        }
        char* dst = (layer ? h1pw : h0pw)
                  + ((u32)(wbuf * 2 + mt) * 32 + (u32)(hb >> 1)) * 2048u + lo16;
        u32x4 vh = {hi[0], hi[1], hi[2], hi[3]};
        u32x4 vl = {lo[0], lo[1], lo[2], lo[3]};
        store16_llc(dst, vh);
        store16_llc(dst + 1024, vl);
      }
    }
    if (s < T_) {
      // release: h-stores are write-through to LLC; just drain them, then count.
      asm volatile("s_waitcnt vmcnt(0)" ::: "memory");
      if (lane == 0)
        __hip_atomic_fetch_add(bar, 1u, __ATOMIC_RELAXED, __HIP_MEMORY_SCOPE_AGENT);
      u32 target = 128u * (u32)(s + 1);
      // RELAXED poll: plain LLC read per iteration, no buffer_inv storm.
      while (__hip_atomic_load(bar, __ATOMIC_RELAXED, __HIP_MEMORY_SCOPE_AGENT) < target)
        __builtin_amdgcn_s_sleep(1);
      // single acquire per step: one buffer_inv so cached h reads refill from LLC
      __builtin_amdgcn_fence(__ATOMIC_ACQUIRE, "agent");
      asm volatile("" ::: "memory");
    }
  }
}

extern "C" void kernel_launch(void* const* d_in, const int* in_sizes, int n_in,
                              void* d_out, int out_size, void* d_ws, size_t ws_size,
                              hipStream_t stream) {
  const float* x    = (const float*)d_in[0];
  const float* Wih0 = (const float*)d_in[1];
  const float* Whh0 = (const float*)d_in[2];
  const float* bih0 = (const float*)d_in[3];
  const float* bhh0 = (const float*)d_in[4];
  const float* Wih1 = (const float*)d_in[5];
  const float* Whh1 = (const float*)d_in[6];
  const float* bih1 = (const float*)d_in[7];
  const float* bhh1 = (const float*)d_in[8];
  const float* h0   = (const float*)d_in[9];
  const float* c0   = (const float*)d_in[10];
  float* out = (float*)d_out;
  char* ws = (char*)d_ws;
  if (ws_size < WS_NEED) return;  // diagnostic: absmax would stay exactly 0.1299

  hipFuncSetAttribute((const void*)k_main,
                      hipFuncAttributeMaxDynamicSharedMemorySize, LDS_TOTAL);

  k_packw<<<1664, 256, 0, stream>>>(Wih0, Whh0, Wih1, Whh1, ws + OFF_W);
  k_packx<<<2048, 256, 0, stream>>>(x, ws + OFF_X);
  k_init<<<177, 256, 0, stream>>>(bih0, bhh0, bih1, bhh1, h0, out, ws);
  k_main<<<256, 64, LDS_TOTAL, stream>>>(ws, c0, out);
}

// Round 4
// 4566.489 us; speedup vs baseline: 5.7714x; 2.6581x over previous
//
#include <hip/hip_runtime.h>
#include <stdint.h>

typedef _Float16 f16;
typedef _Float16 f16x8 __attribute__((ext_vector_type(8)));
typedef float f32x16 __attribute__((ext_vector_type(16)));
typedef uint32_t u32;
typedef u32 u32x4 __attribute__((ext_vector_type(4)));
typedef u32 u32x2 __attribute__((ext_vector_type(2)));

#define T_ 512

// ---- workspace layout (bytes) ----
#define SZ_W0  (64u*40u*2048u)          // layer0 packed weights: 64 hb * 40 ksteps * (1KB hi + 1KB lo)
#define SZ_W1  (64u*64u*2048u)          // layer1
#define OFF_W  0u
#define OFF_X  (SZ_W0 + SZ_W1)
#define SZ_X   (8192u*2048u)            // x packed: 512 t * 2 mt * 8 kc * 2KB
#define OFF_H0 (OFF_X + SZ_X)
#define SZ_HP  (3u*2u*32u*2048u)        // 3 rot bufs * 2 mt * 32 kc * 2KB
#define OFF_H1 (OFF_H0 + SZ_HP)
#define OFF_BIAS (OFF_H1 + SZ_HP)       // f32[2][2048]
#define OFF_BAR  (OFF_BIAS + 16384u)    // flags: u32[128] per mt, mt groups 4KB apart
#define WS_NEED  (size_t)(OFF_BAR + 8192u)

#define LDS_ACC  131072                 // f32[32][33]
#define LDS_H    (131072 + 4352)        // f32[32][9]
#define LDS_TOTAL (131072 + 4352 + 1280)

__device__ __forceinline__ float sigm(float x) { return 1.0f / (1.0f + __expf(-x)); }
__device__ __forceinline__ float tanh_f(float x) {
  float e = __expf(2.0f * x);
  return 1.0f - 2.0f / (e + 1.0f);
}
__device__ __forceinline__ u32 f16bits(f16 v) {
  return (u32)__builtin_bit_cast(unsigned short, v);
}
// write-through store to LLC (bypass L1/L2) -> release needs only vmcnt(0), no buffer_wbl2
__device__ __forceinline__ void store16_llc(void* p, u32x4 v) {
  asm volatile("global_store_dwordx4 %0, %1, off sc0 sc1" :: "v"(p), "v"(v) : "memory");
}
__device__ __forceinline__ void store4_llc(void* p, u32 v) {
  asm volatile("global_store_dword %0, %1, off sc0 sc1" :: "v"(p), "v"(v) : "memory");
}
// LLC-coherent read (bypass L1/L2). NO waitcnt inside: caller MUST s_waitcnt vmcnt(N)
// + sched_barrier(0) before consuming the result (rule #18).
__device__ __forceinline__ f16x8 load16_llc(const void* p) {
  f16x8 r;
  asm volatile("global_load_dwordx4 %0, %1, off sc0 sc1" : "=v"(r) : "v"(p));
  return r;
}
// poll read: load + waitcnt FUSED in one asm block so the output is valid at
// block exit -- rule #18: a separate waitcnt asm does NOT order register-only
// consumers (the round-3 race: v_cmp scheduled between load and waitcnt).
__device__ __forceinline__ u32x2 load8_llc_wait(const void* p) {
  u32x2 r;
  asm volatile("global_load_dwordx2 %0, %1, off sc0 sc1\n\t"
               "s_waitcnt vmcnt(0)"
               : "=v"(r) : "v"(p) : "memory");
  return r;
}

// ---------------- weight prepack ----------------
// frag layout (32x32x16 f16): B[k][n]: lane = n (0..31) + 32*khalf; reg j: k = khalf*8 + j
// col order within 32-col tile: col = gate*8 + h8  (hidden-local h8 in 0..7)
__global__ void k_packw(const float* __restrict__ Wih0, const float* __restrict__ Whh0,
                        const float* __restrict__ Wih1, const float* __restrict__ Whh1,
                        char* __restrict__ wp) {
  int tid = blockIdx.x * 256 + threadIdx.x;
  int unit = tid >> 6, lane = tid & 63;
  if (unit >= 2560 + 4096) return;
  int layer, hb, ks;
  if (unit < 2560) { layer = 0; hb = unit / 40; ks = unit % 40; }
  else { int u = unit - 2560; layer = 1; hb = u >> 6; ks = u & 63; }
  int col = lane & 31;
  int gate = col >> 3, h8 = col & 7;
  int row = gate * 512 + hb * 8 + h8;
  int khalf = lane >> 5;
  u32 hi[4], lo[4];
#pragma unroll
  for (int jp = 0; jp < 4; ++jp) {
    u32 hv = 0, lv = 0;
#pragma unroll
    for (int e = 0; e < 2; ++e) {
      int j = jp * 2 + e;
      int k = ks * 16 + khalf * 8 + j;
      float w;
      if (layer == 0) w = (k < 128) ? Wih0[row * 128 + k] : Whh0[row * 512 + (k - 128)];
      else            w = (k < 512) ? Wih1[row * 512 + k] : Whh1[row * 512 + (k - 512)];
      f16 h_ = (f16)w; f16 l_ = (f16)(w - (float)h_);
      hv |= f16bits(h_) << (16 * e);
      lv |= f16bits(l_) << (16 * e);
    }
    hi[jp] = hv; lo[jp] = lv;
  }
  char* dst = wp + (layer ? SZ_W0 + (u32)hb * 64u * 2048u : (u32)hb * 40u * 2048u)
                 + (u32)ks * 2048u + (u32)lane * 16u;
  u32x4 vh = {hi[0], hi[1], hi[2], hi[3]};
  u32x4 vl = {lo[0], lo[1], lo[2], lo[3]};
  *(u32x4*)dst = vh;
  *(u32x4*)(dst + 1024) = vl;
}

// ---------------- x prepack ----------------
// A[m][k]: lane = m-row (0..31) + 32*khalf; reg j: k = khalf*8 + j  (same k-map as B -> cancels)
__global__ void k_packx(const float* __restrict__ x, char* __restrict__ xp) {
  int tid = blockIdx.x * 256 + threadIdx.x;
  int unit = tid >> 6, lane = tid & 63;   // units: 512*2*8 = 8192
  if (unit >= 8192) return;
  int t = unit >> 4, mt = (unit >> 3) & 1, kc = unit & 7;
  int b = mt * 32 + (lane & 31);
  int kbase = kc * 16 + (lane >> 5) * 8;
  const float* src = x + ((size_t)b * T_ + t) * 128 + kbase;
  u32 hi[4], lo[4];
#pragma unroll
  for (int jp = 0; jp < 4; ++jp) {
    u32 hv = 0, lv = 0;
#pragma unroll
    for (int e = 0; e < 2; ++e) {
      float w = src[jp * 2 + e];
      f16 h_ = (f16)w; f16 l_ = (f16)(w - (float)h_);
      hv |= f16bits(h_) << (16 * e);
      lv |= f16bits(l_) << (16 * e);
    }
    hi[jp] = hv; lo[jp] = lv;
  }
  char* dst = xp + (size_t)unit * 2048 + (u32)lane * 16;
  u32x4 vh = {hi[0], hi[1], hi[2], hi[3]};
  u32x4 vl = {lo[0], lo[1], lo[2], lo[3]};
  *(u32x4*)dst = vh;
  *(u32x4*)(dst + 1024) = vl;
}

// ---------------- init: out row0, h-pack init bufs, biases, flags ----------------
__global__ void k_init(const float* __restrict__ bih0, const float* __restrict__ bhh0,
                       const float* __restrict__ bih1, const float* __restrict__ bhh1,
                       const float* __restrict__ h0in,
                       float* __restrict__ out, char* __restrict__ ws) {
  int tid = blockIdx.x * 256 + threadIdx.x;
  if (tid < 32768) {                       // out[:,0,:] = h0[-1,0,:]
    int b = tid >> 9, h = tid & 511;
    out[(size_t)b * 513 * 512 + h] = h0in[512 + h];
  } else if (tid < 32768 + 8192) {         // h-pack init: layer0 -> buf2, layer1 -> buf0
    int q = tid - 32768; int unit = q >> 6, lane = q & 63;  // 128 units
    int layer = unit >> 6, mt = (unit >> 5) & 1, kc = unit & 31;
    int Hh = kc * 16 + (lane >> 5) * 8;
    u32 hi[4], lo[4];
#pragma unroll
    for (int jp = 0; jp < 4; ++jp) {
      u32 hv = 0, lv = 0;
#pragma unroll
      for (int e = 0; e < 2; ++e) {
        float w = h0in[layer * 512 + Hh + jp * 2 + e];
        f16 h_ = (f16)w; f16 l_ = (f16)(w - (float)h_);
        hv |= f16bits(h_) << (16 * e);
        lv |= f16bits(l_) << (16 * e);
      }
      hi[jp] = hv; lo[jp] = lv;
    }
    int buf = layer ? 0 : 2;
    char* dst = ws + (layer ? OFF_H1 : OFF_H0)
                   + ((u32)(buf * 2 + mt) * 32 + (u32)kc) * 2048u + (u32)lane * 16u;
    u32x4 vh = {hi[0], hi[1], hi[2], hi[3]};
    u32x4 vl = {lo[0], lo[1], lo[2], lo[3]};
    *(u32x4*)dst = vh;
    *(u32x4*)(dst + 1024) = vl;
  } else if (tid < 32768 + 8192 + 4096) {  // combined biases
    int j = tid - 40960; int layer = j >> 11, jj = j & 2047;
    const float* a = layer ? bih1 : bih0;
    const float* b2 = layer ? bhh1 : bhh0;
    ((float*)(ws + OFF_BIAS))[layer * 2048 + jj] = a[jj] + b2[jj];
  } else if (tid < 45056 + 256) {          // zero flag arrays: u32[128] per mt
    int g = tid - 45056; int mt = g >> 7, idx = g & 127;
    *(u32*)(ws + OFF_BAR + (u32)mt * 4096u + (u32)idx * 4u) = 0u;
  }
}

// issue 16 LLC loads for one 8-ks block into register buffers (no waits)
#define ISSUE_BLOCK(AH, AL, bb) \
  _Pragma("unroll") for (int i_ = 0; i_ < 8; ++i_) { \
    AH[i_] = load16_llc((bb) + (u32)i_ * 2048u + lo16); \
    AL[i_] = load16_llc((bb) + (u32)i_ * 2048u + 1024u + lo16); }

#define MFMA_BLOCK(AH, AL, BLK) \
  _Pragma("unroll") for (int i_ = 0; i_ < 8; ++i_) { \
    f16x8 bhi_ = *(const f16x8*)(smem + (u32)((BLK) * 8 + i_) * 2048u + lo16); \
    f16x8 blo_ = *(const f16x8*)(smem + (u32)((BLK) * 8 + i_) * 2048u + 1024u + lo16); \
    accA = __builtin_amdgcn_mfma_f32_32x32x16_f16(AH[i_], bhi_, accA, 0, 0, 0); \
    accB = __builtin_amdgcn_mfma_f32_32x32x16_f16(AH[i_], blo_, accB, 0, 0, 0); \
    accC = __builtin_amdgcn_mfma_f32_32x32x16_f16(AL[i_], bhi_, accC, 0, 0, 0); }

#define BBASE(B) ((B) < splitblk ? a0 + (u32)(B) * 16384u : a1 + (u32)((B) - splitblk) * 16384u)

// ---------------- persistent recurrent kernel ----------------
// 256 WGs x 64 threads. wg -> (mt, layer, hb8). One 32x32 output tile per WG.
// LDS 133KB forces 1 WG/CU -> all 256 co-resident.
// Sync: per-WG epoch flag (write-through LLC store) + wave-parallel flag poll.
// No atomics, no buffer_inv: all cross-step data moves through LLC via sc0 sc1.
__global__ __launch_bounds__(64, 1)
void k_main(char* ws, const float* c0in, float* __restrict__ out) {
  extern __shared__ char smem[];
  const int wg = blockIdx.x;
  const int mt = wg & 1, layer = (wg >> 1) & 1, hb = wg >> 2;
  const int lane = threadIdx.x;
  const int nk = layer ? 64 : 40;
  const int nb = layer ? 8 : 5;         // 8-ks blocks
  const int splitblk = layer ? 4 : 1;   // blocks sourced from a0

  // weights -> LDS (persistent; L2 never invalidated in this design)
  {
    const char* wsrc = ws + OFF_W + (layer ? SZ_W0 + (u32)hb * 64u * 2048u : (u32)hb * 40u * 2048u);
    int nbytes = nk * 2048;
    for (int off = lane * 16; off < nbytes; off += 1024)
      *(u32x4*)(smem + off) = *(const u32x4*)(wsrc + off);
  }
  float* accS = (float*)(smem + LDS_ACC);   // [32][33]
  float* hS   = (float*)(smem + LDS_H);     // [32][9]
  const float* bias = (const float*)(ws + OFF_BIAS) + layer * 2048;
  const int hl = lane & 7, rg = lane >> 3;
  const int Hid = hb * 8 + hl;
  const float bi = bias[0 * 512 + Hid], bf = bias[1 * 512 + Hid];
  const float bg = bias[2 * 512 + Hid], bo = bias[3 * 512 + Hid];
  float c[4];
  { float ci = c0in[layer * 512 + Hid]; c[0] = c[1] = c[2] = c[3] = ci; }
  u32* flags = (u32*)(ws + OFF_BAR + (u32)mt * 4096u);  // u32[128]: [layer*64 + hb]
  const u32* myflagp = flags + (u32)lane * 2u;          // this lane polls 2 flags
  u32* myslot = flags + ((u32)layer * 64u + (u32)hb);
  // poll target offset: lane<32 covers L0 flags (everyone needs >= s+1);
  // lane>=32 covers L1 flags (L1 needs >= s+1; L0 only >= s -- 1-step lag, WAR-safe
  // under the 3-buffer rotation: L0@sigma overwrites the buf L1 read at sigma-2).
  const u32 tgt_sub = (lane >= 32 && layer == 0) ? 1u : 0u;
  const char* xp  = ws + OFF_X;
  const char* h0p = ws + OFF_H0;
  const char* h1p = ws + OFF_H1;
  const u32 lo16 = (u32)lane * 16u;
  f16x8 Ah0[8], Al0[8], Ah1[8], Al1[8];
  __syncthreads();

  for (int s = 0; s <= T_; ++s) {
    const bool active = layer ? (s >= 1) : (s < T_);
    if (active) {
      const int t = layer ? (s - 1) : s;
      const int rbuf = (s + 2) % 3, wbuf = s % 3;
      const char* a0; const char* a1;
      if (layer == 0) {
        a0 = xp + (u32)(t * 2 + mt) * 8u * 2048u;
        a1 = h0p + ((u32)(rbuf * 2 + mt) * 32u) * 2048u;
      } else {
        a0 = h0p + ((u32)(rbuf * 2 + mt) * 32u) * 2048u;
        a1 = h1p + ((u32)(rbuf * 2 + mt) * 32u) * 2048u;
      }
      f32x16 accA = {}, accB = {}, accC = {};
      // double-buffered counted pipeline: 16 LLC loads per 8-ks block in flight.
      // Every counted wait is followed by sched_barrier(0) (rule #18) so no
      // register-only consumer can be scheduled above it.
      ISSUE_BLOCK(Ah0, Al0, BBASE(0));
#pragma unroll
      for (int blk = 0; blk < 8; blk += 2) if (blk < nb) {
        if (blk + 1 < nb) { ISSUE_BLOCK(Ah1, Al1, BBASE(blk + 1));
                            asm volatile("s_waitcnt vmcnt(16)" ::: "memory"); }
        else              { asm volatile("s_waitcnt vmcnt(0)" ::: "memory"); }
        __builtin_amdgcn_sched_barrier(0);
        MFMA_BLOCK(Ah0, Al0, blk);
        if (blk + 1 < nb) {
          if (blk + 2 < nb) { ISSUE_BLOCK(Ah0, Al0, BBASE(blk + 2));
                              asm volatile("s_waitcnt vmcnt(16)" ::: "memory"); }
          else              { asm volatile("s_waitcnt vmcnt(0)" ::: "memory"); }
          __builtin_amdgcn_sched_barrier(0);
          MFMA_BLOCK(Ah1, Al1, blk + 1);
        }
      }
      // C layout (verified m74/m101): col = lane&31, row = (reg&3) + 8*(reg>>2) + 4*(lane>>5)
#pragma unroll
      for (int r = 0; r < 16; ++r) {
        int row = (r & 3) + 8 * (r >> 2) + 4 * (lane >> 5);
        accS[row * 33 + (lane & 31)] = accA[r] + accB[r] + accC[r];
      }
      __syncthreads();
      float* outp = out + (size_t)(mt * 32) * 513 * 512 + (size_t)(t + 1) * 512 + Hid;
#pragma unroll
      for (int j = 0; j < 4; ++j) {
        int row = rg * 4 + j;
        float gi = accS[row * 33 + hl] + bi;
        float gf = accS[row * 33 + 8 + hl] + bf;
        float gg = accS[row * 33 + 16 + hl] + bg;
        float go = accS[row * 33 + 24 + hl] + bo;
        float iv = sigm(gi), fv = sigm(gf), gv = tanh_f(gg), ov = sigm(go);
        float cc = fv * c[j] + iv * gv; c[j] = cc;
        float hv = ov * tanh_f(cc);
        hS[row * 9 + hl] = hv;
        if (layer) outp[(size_t)row * 513 * 512] = hv;
      }
      __syncthreads();
      // pack h into next-step A-frag layout; this WG owns k16-half (hb&1) of kchunk hb>>1.
      // Write-through to LLC -> no buffer_wbl2 needed at release.
      if ((lane >> 5) == (hb & 1)) {
        int r32 = lane & 31;
        u32 hi[4], lo[4];
#pragma unroll
        for (int jp = 0; jp < 4; ++jp) {
          float v0 = hS[r32 * 9 + jp * 2], v1 = hS[r32 * 9 + jp * 2 + 1];
          f16 a_ = (f16)v0; f16 b_ = (f16)(v0 - (float)a_);
          f16 c_ = (f16)v1; f16 d_ = (f16)(v1 - (float)c_);
          hi[jp] = f16bits(a_) | (f16bits(c_) << 16);
          lo[jp] = f16bits(b_) | (f16bits(d_) << 16);
        }
        char* dst = (char*)(layer ? h1p : h0p)
                  + ((u32)(wbuf * 2 + mt) * 32 + (u32)(hb >> 1)) * 2048u + lo16;
        u32x4 vh = {hi[0], hi[1], hi[2], hi[3]};
        u32x4 vl = {lo[0], lo[1], lo[2], lo[3]};
        store16_llc(dst, vh);
        store16_llc(dst + 1024, vl);
      }
    }
    if (s < T_) {
      // release: drain write-through h stores (+ out stores), then publish epoch flag
      asm volatile("s_waitcnt vmcnt(0)" ::: "memory");
      if (lane == 0) store4_llc(myslot, (u32)(s + 1));
      // wave-parallel flag poll: 64 lanes x 2 flags = all 128 group members per RTT.
      // load+waitcnt fused in ONE asm block (rule #18: the round-3 bug was a
      // separate waitcnt asm -- the compare got scheduled before the wait).
      const u32 tgt = (u32)(s + 1) - tgt_sub;
      for (;;) {
        u32x2 v = load8_llc_wait(myflagp);
        __builtin_amdgcn_sched_barrier(0);
        if (__all((v.x >= tgt) && (v.y >= tgt))) break;
        __builtin_amdgcn_s_sleep(1);
      }
      __builtin_amdgcn_sched_barrier(0);
      asm volatile("" ::: "memory");
    }
  }
}

extern "C" void kernel_launch(void* const* d_in, const int* in_sizes, int n_in,
                              void* d_out, int out_size, void* d_ws, size_t ws_size,
                              hipStream_t stream) {
  const float* x    = (const float*)d_in[0];
  const float* Wih0 = (const float*)d_in[1];
  const float* Whh0 = (const float*)d_in[2];
  const float* bih0 = (const float*)d_in[3];
  const float* bhh0 = (const float*)d_in[4];
  const float* Wih1 = (const float*)d_in[5];
  const float* Whh1 = (const float*)d_in[6];
  const float* bih1 = (const float*)d_in[7];
  const float* bhh1 = (const float*)d_in[8];
  const float* h0   = (const float*)d_in[9];
  const float* c0   = (const float*)d_in[10];
  float* out = (float*)d_out;
  char* ws = (char*)d_ws;
  if (ws_size < WS_NEED) return;  // diagnostic: absmax would stay exactly 0.1299

  hipFuncSetAttribute((const void*)k_main,
                      hipFuncAttributeMaxDynamicSharedMemorySize, LDS_TOTAL);

  k_packw<<<1664, 256, 0, stream>>>(Wih0, Whh0, Wih1, Whh1, ws + OFF_W);
  k_packx<<<2048, 256, 0, stream>>>(x, ws + OFF_X);
  k_init<<<177, 256, 0, stream>>>(bih0, bhh0, bih1, bhh1, h0, out, ws);
  k_main<<<256, 64, LDS_TOTAL, stream>>>(ws, c0, out);
}

// Round 5
// 4007.635 us; speedup vs baseline: 6.5762x; 1.1394x over previous
//
#include <hip/hip_runtime.h>
#include <stdint.h>

typedef _Float16 f16;
typedef _Float16 f16x8 __attribute__((ext_vector_type(8)));
typedef float f32x16 __attribute__((ext_vector_type(16)));
typedef uint32_t u32;
typedef u32 u32x4 __attribute__((ext_vector_type(4)));
typedef u32 u32x2 __attribute__((ext_vector_type(2)));

#define T_ 512

// ---- workspace layout (bytes) ----
#define SZ_W0  (64u*40u*2048u)          // layer0 packed weights: 64 hb * 40 ksteps * (1KB hi + 1KB lo)
#define SZ_W1  (64u*64u*2048u)          // layer1
#define OFF_W  0u
#define OFF_X  (SZ_W0 + SZ_W1)
#define SZ_X   (8192u*2048u)            // x packed: 512 t * 2 mt * 8 kc * 2KB
#define OFF_H0 (OFF_X + SZ_X)
#define SZ_HP  (3u*2u*32u*2048u)        // 3 rot bufs * 2 mt * 32 kc * 2KB
#define OFF_H1 (OFF_H0 + SZ_HP)
#define OFF_BIAS (OFF_H1 + SZ_HP)       // f32[2][2048]
#define OFF_BAR  (OFF_BIAS + 16384u)    // flags: u32[128] per mt, mt groups 4KB apart
#define WS_NEED  (size_t)(OFF_BAR + 8192u)

#define LDS_ACC  131072                 // f32[4][32][33] partial accs (one per wave)
#define LDS_H    (131072 + 16896)       // f32[32][9]
#define LDS_TOTAL (131072 + 16896 + 1152)

__device__ __forceinline__ float sigm(float x) { return 1.0f / (1.0f + __expf(-x)); }
__device__ __forceinline__ float tanh_f(float x) {
  float e = __expf(2.0f * x);
  return 1.0f - 2.0f / (e + 1.0f);
}
__device__ __forceinline__ u32 f16bits(f16 v) {
  return (u32)__builtin_bit_cast(unsigned short, v);
}
// write-through store to LLC (bypass L1/L2) -> release needs only vmcnt(0), no buffer_wbl2
__device__ __forceinline__ void store16_llc(void* p, u32x4 v) {
  asm volatile("global_store_dwordx4 %0, %1, off sc0 sc1" :: "v"(p), "v"(v) : "memory");
}
__device__ __forceinline__ void store4_llc(void* p, u32 v) {
  asm volatile("global_store_dword %0, %1, off sc0 sc1" :: "v"(p), "v"(v) : "memory");
}
// LLC-coherent read (bypass L1/L2). NO waitcnt inside: caller MUST s_waitcnt vmcnt(N)
// + sched_barrier(0) before consuming the result (rule #18).
__device__ __forceinline__ f16x8 load16_llc(const void* p) {
  f16x8 r;
  asm volatile("global_load_dwordx4 %0, %1, off sc0 sc1" : "=v"(r) : "v"(p));
  return r;
}
// poll read: load + waitcnt FUSED in one asm block so the output is valid at
// block exit (rule #18: a separate waitcnt asm does NOT order register-only
// consumers -- the round-3 race).
__device__ __forceinline__ u32x2 load8_llc_wait(const void* p) {
  u32x2 r;
  asm volatile("global_load_dwordx2 %0, %1, off sc0 sc1\n\t"
               "s_waitcnt vmcnt(0)"
               : "=v"(r) : "v"(p) : "memory");
  return r;
}

// ---------------- weight prepack ----------------
// frag layout (32x32x16 f16): B[k][n]: lane = n (0..31) + 32*khalf; reg j: k = khalf*8 + j
// col order within 32-col tile: col = gate*8 + h8  (hidden-local h8 in 0..7)
__global__ void k_packw(const float* __restrict__ Wih0, const float* __restrict__ Whh0,
                        const float* __restrict__ Wih1, const float* __restrict__ Whh1,
                        char* __restrict__ wp) {
  int tid = blockIdx.x * 256 + threadIdx.x;
  int unit = tid >> 6, lane = tid & 63;
  if (unit >= 2560 + 4096) return;
  int layer, hb, ks;
  if (unit < 2560) { layer = 0; hb = unit / 40; ks = unit % 40; }
  else { int u = unit - 2560; layer = 1; hb = u >> 6; ks = u & 63; }
  int col = lane & 31;
  int gate = col >> 3, h8 = col & 7;
  int row = gate * 512 + hb * 8 + h8;
  int khalf = lane >> 5;
  u32 hi[4], lo[4];
#pragma unroll
  for (int jp = 0; jp < 4; ++jp) {
    u32 hv = 0, lv = 0;
#pragma unroll
    for (int e = 0; e < 2; ++e) {
      int j = jp * 2 + e;
      int k = ks * 16 + khalf * 8 + j;
      float w;
      if (layer == 0) w = (k < 128) ? Wih0[row * 128 + k] : Whh0[row * 512 + (k - 128)];
      else            w = (k < 512) ? Wih1[row * 512 + k] : Whh1[row * 512 + (k - 512)];
      f16 h_ = (f16)w; f16 l_ = (f16)(w - (float)h_);
      hv |= f16bits(h_) << (16 * e);
      lv |= f16bits(l_) << (16 * e);
    }
    hi[jp] = hv; lo[jp] = lv;
  }
  char* dst = wp + (layer ? SZ_W0 + (u32)hb * 64u * 2048u : (u32)hb * 40u * 2048u)
                 + (u32)ks * 2048u + (u32)lane * 16u;
  u32x4 vh = {hi[0], hi[1], hi[2], hi[3]};
  u32x4 vl = {lo[0], lo[1], lo[2], lo[3]};
  *(u32x4*)dst = vh;
  *(u32x4*)(dst + 1024) = vl;
}

// ---------------- x prepack ----------------
// A[m][k]: lane = m-row (0..31) + 32*khalf; reg j: k = khalf*8 + j  (same k-map as B -> cancels)
__global__ void k_packx(const float* __restrict__ x, char* __restrict__ xp) {
  int tid = blockIdx.x * 256 + threadIdx.x;
  int unit = tid >> 6, lane = tid & 63;   // units: 512*2*8 = 8192
  if (unit >= 8192) return;
  int t = unit >> 4, mt = (unit >> 3) & 1, kc = unit & 7;
  int b = mt * 32 + (lane & 31);
  int kbase = kc * 16 + (lane >> 5) * 8;
  const float* src = x + ((size_t)b * T_ + t) * 128 + kbase;
  u32 hi[4], lo[4];
#pragma unroll
  for (int jp = 0; jp < 4; ++jp) {
    u32 hv = 0, lv = 0;
#pragma unroll
    for (int e = 0; e < 2; ++e) {
      float w = src[jp * 2 + e];
      f16 h_ = (f16)w; f16 l_ = (f16)(w - (float)h_);
      hv |= f16bits(h_) << (16 * e);
      lv |= f16bits(l_) << (16 * e);
    }
    hi[jp] = hv; lo[jp] = lv;
  }
  char* dst = xp + (size_t)unit * 2048 + (u32)lane * 16;
  u32x4 vh = {hi[0], hi[1], hi[2], hi[3]};
  u32x4 vl = {lo[0], lo[1], lo[2], lo[3]};
  *(u32x4*)dst = vh;
  *(u32x4*)(dst + 1024) = vl;
}

// ---------------- init: out row0, h-pack init bufs, biases, flags ----------------
__global__ void k_init(const float* __restrict__ bih0, const float* __restrict__ bhh0,
                       const float* __restrict__ bih1, const float* __restrict__ bhh1,
                       const float* __restrict__ h0in,
                       float* __restrict__ out, char* __restrict__ ws) {
  int tid = blockIdx.x * 256 + threadIdx.x;
  if (tid < 32768) {                       // out[:,0,:] = h0[-1,0,:]
    int b = tid >> 9, h = tid & 511;
    out[(size_t)b * 513 * 512 + h] = h0in[512 + h];
  } else if (tid < 32768 + 8192) {         // h-pack init: layer0 -> buf2, layer1 -> buf0
    int q = tid - 32768; int unit = q >> 6, lane = q & 63;  // 128 units
    int layer = unit >> 6, mt = (unit >> 5) & 1, kc = unit & 31;
    int Hh = kc * 16 + (lane >> 5) * 8;
    u32 hi[4], lo[4];
#pragma unroll
    for (int jp = 0; jp < 4; ++jp) {
      u32 hv = 0, lv = 0;
#pragma unroll
      for (int e = 0; e < 2; ++e) {
        float w = h0in[layer * 512 + Hh + jp * 2 + e];
        f16 h_ = (f16)w; f16 l_ = (f16)(w - (float)h_);
        hv |= f16bits(h_) << (16 * e);
        lv |= f16bits(l_) << (16 * e);
      }
      hi[jp] = hv; lo[jp] = lv;
    }
    int buf = layer ? 0 : 2;
    char* dst = ws + (layer ? OFF_H1 : OFF_H0)
                   + ((u32)(buf * 2 + mt) * 32 + (u32)kc) * 2048u + (u32)lane * 16u;
    u32x4 vh = {hi[0], hi[1], hi[2], hi[3]};
    u32x4 vl = {lo[0], lo[1], lo[2], lo[3]};
    *(u32x4*)dst = vh;
    *(u32x4*)(dst + 1024) = vl;
  } else if (tid < 32768 + 8192 + 4096) {  // combined biases
    int j = tid - 40960; int layer = j >> 11, jj = j & 2047;
    const float* a = layer ? bih1 : bih0;
    const float* b2 = layer ? bhh1 : bhh0;
    ((float*)(ws + OFF_BIAS))[layer * 2048 + jj] = a[jj] + b2[jj];
  } else if (tid < 45056 + 256) {          // zero flag arrays: u32[128] per mt
    int g = tid - 45056; int mt = g >> 7, idx = g & 127;
    *(u32*)(ws + OFF_BAR + (u32)mt * 4096u + (u32)idx * 4u) = 0u;
  }
}

// ---- per-wave K-quarter MFMA: issue ALL loads, ONE counted wait, MFMA ----
template<int LKS, int SPLITKS>
__device__ __forceinline__ void k_step_mfma(const char* a0, const char* a1,
                                            const char* smem, int k0, u32 lo16,
                                            f32x16& accA, f32x16& accB, f32x16& accC) {
  f16x8 Ah[LKS], Al[LKS];
#pragma unroll
  for (int i = 0; i < LKS; ++i) {
    int ks = k0 + i;
    const char* ab = (ks < SPLITKS) ? (a0 + (u32)ks * 2048u)
                                    : (a1 + (u32)(ks - SPLITKS) * 2048u);
    Ah[i] = load16_llc(ab + lo16);
    Al[i] = load16_llc(ab + 1024u + lo16);
  }
  constexpr int C1 = (LKS > 8) ? 8 : LKS;
  constexpr int W1 = 2 * (LKS - C1);
  if constexpr (W1 == 16)     asm volatile("s_waitcnt vmcnt(16)" ::: "memory");
  else if constexpr (W1 == 4) asm volatile("s_waitcnt vmcnt(4)" ::: "memory");
  else                        asm volatile("s_waitcnt vmcnt(0)" ::: "memory");
  __builtin_amdgcn_sched_barrier(0);
#pragma unroll
  for (int i = 0; i < C1; ++i) {
    f16x8 bhi = *(const f16x8*)(smem + (u32)(k0 + i) * 2048u + lo16);
    f16x8 blo = *(const f16x8*)(smem + (u32)(k0 + i) * 2048u + 1024u + lo16);
    accA = __builtin_amdgcn_mfma_f32_32x32x16_f16(Ah[i], bhi, accA, 0, 0, 0);
    accB = __builtin_amdgcn_mfma_f32_32x32x16_f16(Ah[i], blo, accB, 0, 0, 0);
    accC = __builtin_amdgcn_mfma_f32_32x32x16_f16(Al[i], bhi, accC, 0, 0, 0);
  }
  if constexpr (LKS > C1) {
    asm volatile("s_waitcnt vmcnt(0)" ::: "memory");
    __builtin_amdgcn_sched_barrier(0);
#pragma unroll
    for (int i = C1; i < LKS; ++i) {
      f16x8 bhi = *(const f16x8*)(smem + (u32)(k0 + i) * 2048u + lo16);
      f16x8 blo = *(const f16x8*)(smem + (u32)(k0 + i) * 2048u + 1024u + lo16);
      accA = __builtin_amdgcn_mfma_f32_32x32x16_f16(Ah[i], bhi, accA, 0, 0, 0);
      accB = __builtin_amdgcn_mfma_f32_32x32x16_f16(Ah[i], blo, accB, 0, 0, 0);
      accC = __builtin_amdgcn_mfma_f32_32x32x16_f16(Al[i], bhi, accC, 0, 0, 0);
    }
  }
}

// ---------------- persistent recurrent kernel ----------------
// 256 WGs x 256 threads (4 waves). wg -> (mt, layer, hb8); wave wv owns K-quarter
// [wv*LKS, (wv+1)*LKS). Each wave: 1 counted wait for ALL its A loads (the round-4
// version had 8 serialized block-waits -> RTT-chain). Partial accs meet in LDS;
// gates computed 4x-parallel. Intra-WG step ordering: waves 1-3 block on their own
// WG's flag at the poll, which wave0 publishes only after the h-pack -> no WAR race.
// LDS 145.6KB forces 1 WG/CU -> all 256 co-resident.
__global__ __launch_bounds__(256, 1)
void k_main(char* ws, const float* c0in, float* __restrict__ out) {
  extern __shared__ char smem[];
  const int wg = blockIdx.x;
  const int mt = wg & 1, layer = (wg >> 1) & 1, hb = wg >> 2;
  const int tid = threadIdx.x;
  const int l = tid & 63;          // lane in wave
  const int wv = tid >> 6;         // wave 0..3
  const int nk = layer ? 64 : 40;

  // weights -> LDS (persistent; L2 never invalidated in this design)
  {
    const char* wsrc = ws + OFF_W + (layer ? SZ_W0 + (u32)hb * 64u * 2048u : (u32)hb * 40u * 2048u);
    int nbytes = nk * 2048;
    for (int off = tid * 16; off < nbytes; off += 4096)
      *(u32x4*)(smem + off) = *(const u32x4*)(wsrc + off);
  }
  float* accP = (float*)(smem + LDS_ACC);   // [4][32][33] partials
  float* hS   = (float*)(smem + LDS_H);     // [32][9]
  const float* bias = (const float*)(ws + OFF_BIAS) + layer * 2048;
  const int hl = tid & 7;
  const int rloc = wv * 8 + ((tid >> 3) & 7);   // this thread's batch row (0..31)
  const int Hid = hb * 8 + hl;
  const float bi = bias[0 * 512 + Hid], bf = bias[1 * 512 + Hid];
  const float bg = bias[2 * 512 + Hid], bo = bias[3 * 512 + Hid];
  float c = c0in[layer * 512 + Hid];            // one c per (rloc, Hid) owner thread
  u32* flags = (u32*)(ws + OFF_BAR + (u32)mt * 4096u);  // u32[128]: [layer*64 + hb]
  const u32* myflagp = flags + (u32)l * 2u;     // each wave polls all 128 flags
  u32* myslot = flags + ((u32)layer * 64u + (u32)hb);
  // lane>=32 covers L1 flags (L1 needs >= s+1; L0 only >= s -- 1-step lag, WAR-safe
  // under the 3-buffer rotation).
  const u32 tgt_sub = (l >= 32 && layer == 0) ? 1u : 0u;
  const char* xp  = ws + OFF_X;
  const char* h0p = ws + OFF_H0;
  const char* h1p = ws + OFF_H1;
  const u32 lo16 = (u32)l * 16u;
  const int k0 = wv * (layer ? 16 : 10);
  __syncthreads();

  for (int s = 0; s <= T_; ++s) {
    const bool active = layer ? (s >= 1) : (s < T_);
    if (active) {
      const int t = layer ? (s - 1) : s;
      const int rbuf = (s + 2) % 3, wbuf = s % 3;
      const char* a0; const char* a1;
      if (layer == 0) {
        a0 = xp + (u32)(t * 2 + mt) * 8u * 2048u;
        a1 = h0p + ((u32)(rbuf * 2 + mt) * 32u) * 2048u;
      } else {
        a0 = h0p + ((u32)(rbuf * 2 + mt) * 32u) * 2048u;
        a1 = h1p + ((u32)(rbuf * 2 + mt) * 32u) * 2048u;
      }
      f32x16 accA = {}, accB = {}, accC = {};
      if (layer == 0) k_step_mfma<10, 8 >(a0, a1, smem, k0, lo16, accA, accB, accC);
      else            k_step_mfma<16, 32>(a0, a1, smem, k0, lo16, accA, accB, accC);
      // write this wave's partial: C layout (m74/m101): col=lane&31,
      // row=(reg&3)+8*(reg>>2)+4*(lane>>5)
      {
        float* ap = accP + wv * 1056;
#pragma unroll
        for (int r = 0; r < 16; ++r) {
          int row = (r & 3) + 8 * (r >> 2) + 4 * (l >> 5);
          ap[row * 33 + (l & 31)] = accA[r] + accB[r] + accC[r];
        }
      }
      __syncthreads();
      // gates: one (row, hidden) per thread, summing the 4 wave-partials
      {
        float gi = bi, gf = bf, gg = bg, go = bo;
#pragma unroll
        for (int p = 0; p < 4; ++p) {
          const float* ap = accP + p * 1056 + rloc * 33;
          gi += ap[hl]; gf += ap[8 + hl]; gg += ap[16 + hl]; go += ap[24 + hl];
        }
        float iv = sigm(gi), fv = sigm(gf), gv = tanh_f(gg), ov = sigm(go);
        c = fv * c + iv * gv;
        float hv = ov * tanh_f(c);
        hS[rloc * 9 + hl] = hv;
        if (layer)
          out[(size_t)(mt * 32 + rloc) * 513 * 512 + (size_t)(t + 1) * 512 + Hid] = hv;
      }
      __syncthreads();
      // pack h into next-step A-frag layout (wave 0, half selected by hb&1).
      // Write-through to LLC -> no buffer_wbl2 needed at release.
      if (wv == 0 && (l >> 5) == (hb & 1)) {
        int r32 = l & 31;
        u32 hi[4], lo[4];
#pragma unroll
        for (int jp = 0; jp < 4; ++jp) {
          float v0 = hS[r32 * 9 + jp * 2], v1 = hS[r32 * 9 + jp * 2 + 1];
          f16 a_ = (f16)v0; f16 b_ = (f16)(v0 - (float)a_);
          f16 c_ = (f16)v1; f16 d_ = (f16)(v1 - (float)c_);
          hi[jp] = f16bits(a_) | (f16bits(c_) << 16);
          lo[jp] = f16bits(b_) | (f16bits(d_) << 16);
        }
        char* dst = (char*)(layer ? h1p : h0p)
                  + ((u32)(wbuf * 2 + mt) * 32 + (u32)(hb >> 1)) * 2048u + lo16;
        u32x4 vh = {hi[0], hi[1], hi[2], hi[3]};
        u32x4 vl = {lo[0], lo[1], lo[2], lo[3]};
        store16_llc(dst, vh);
        store16_llc(dst + 1024, vl);
      }
    }
    if (s < T_) {
      // release: drain write-through h stores (wave0: pack; others: out), then flag
      asm volatile("s_waitcnt vmcnt(0)" ::: "memory");
      if (tid == 0) store4_llc(myslot, (u32)(s + 1));
      // wave-parallel flag poll (per wave): 64 lanes x 2 flags = all 128 members.
      // load+waitcnt fused in ONE asm block (rule #18).
      const u32 tgt = (u32)(s + 1) - tgt_sub;
      for (;;) {
        u32x2 v = load8_llc_wait(myflagp);
        __builtin_amdgcn_sched_barrier(0);
        if (__all((v.x >= tgt) && (v.y >= tgt))) break;
        __builtin_amdgcn_s_sleep(1);
      }
      __builtin_amdgcn_sched_barrier(0);
      asm volatile("" ::: "memory");
    }
  }
}

extern "C" void kernel_launch(void* const* d_in, const int* in_sizes, int n_in,
                              void* d_out, int out_size, void* d_ws, size_t ws_size,
                              hipStream_t stream) {
  const float* x    = (const float*)d_in[0];
  const float* Wih0 = (const float*)d_in[1];
  const float* Whh0 = (const float*)d_in[2];
  const float* bih0 = (const float*)d_in[3];
  const float* bhh0 = (const float*)d_in[4];
  const float* Wih1 = (const float*)d_in[5];
  const float* Whh1 = (const float*)d_in[6];
  const float* bih1 = (const float*)d_in[7];
  const float* bhh1 = (const float*)d_in[8];
  const float* h0   = (const float*)d_in[9];
  const float* c0   = (const float*)d_in[10];
  float* out = (float*)d_out;
  char* ws = (char*)d_ws;
  if (ws_size < WS_NEED) return;  // diagnostic: absmax would stay exactly 0.1299

  hipFuncSetAttribute((const void*)k_main,
                      hipFuncAttributeMaxDynamicSharedMemorySize, LDS_TOTAL);

  k_packw<<<1664, 256, 0, stream>>>(Wih0, Whh0, Wih1, Whh1, ws + OFF_W);
  k_packx<<<2048, 256, 0, stream>>>(x, ws + OFF_X);
  k_init<<<177, 256, 0, stream>>>(bih0, bhh0, bih1, bhh1, h0, out, ws);
  k_main<<<256, 256, LDS_TOTAL, stream>>>(ws, c0, out);
}